// Round 17
// baseline (123.388 us; speedup 1.0000x reference)
//
#include <hip/hip_runtime.h>
#include <math.h>

#define NH 16
#define KD 64
#define DMODEL 1024
#define BATCH 2
#define SEQ 2048
#define MROWS (BATCH*SEQ)

typedef float f32x4 __attribute__((ext_vector_type(4)));
typedef float f32x16 __attribute__((ext_vector_type(16)));
typedef __bf16 bf16x8 __attribute__((ext_vector_type(8)));

__device__ __forceinline__ unsigned short f2bf(float x) {
    union { float f; unsigned u; } a; a.f = x;
    unsigned r = a.u + 0x7fffu + ((a.u >> 16) & 1u);
    return (unsigned short)(r >> 16);
}
__device__ __forceinline__ unsigned cvt_pk_bf16(float lo, float hi) {
    unsigned r;
    asm("v_cvt_pk_bf16_f32 %0, %1, %2" : "=v"(r) : "v"(lo), "v"(hi));
    return r;
}
__device__ __forceinline__ float exp2_hw(float x) {
    float r;
    asm("v_exp_f32 %0, %1" : "=v"(r) : "v"(x));
    return r;
}

__device__ __forceinline__ void gl2lds16(const void* gsrc, void* ldst) {
    __builtin_amdgcn_global_load_lds(
        (const __attribute__((address_space(1))) void*)gsrc,
        (__attribute__((address_space(3))) void*)ldst, 16, 0, 0);
}

// ---------------------------------------------------------------------------
// Fused prep: [0,256) rope tables; [256,4352) cvt_x; [4352,5376) cvt_w4.
// ---------------------------------------------------------------------------
__global__ __launch_bounds__(256) void k_prep(const float* __restrict__ x,
                                              const float* __restrict__ W0,
                                              const float* __restrict__ W1,
                                              const float* __restrict__ W2,
                                              const float* __restrict__ W3,
                                              float* __restrict__ sin_t,
                                              float* __restrict__ cos_t,
                                              unsigned short* __restrict__ xh,
                                              unsigned short* __restrict__ Th) {
    __shared__ float L[64][65];
    const int bid = blockIdx.x;
    const int tid = threadIdx.x;
    if (bid < 256) {
        int idx = bid * 256 + tid;
        int s = idx >> 5, i = idx & 31;
        float invf = expf((float)(2 * i) * (-logf(10000.0f) / (float)KD));
        float ang = (float)s * invf;
        sin_t[idx] = sinf(ang);
        cos_t[idx] = cosf(ang);
        return;
    }
    if (bid < 4352) {
        int idx = (bid - 256) * 256 + tid;
        float4 v = reinterpret_cast<const float4*>(x)[idx];
        ushort4 h;
        h.x = f2bf(v.x); h.y = f2bf(v.y); h.z = f2bf(v.z); h.w = f2bf(v.w);
        reinterpret_cast<ushort4*>(xh)[idx] = h;
        return;
    }
    int r = bid - 4352;
    int z = r >> 8;
    int rr = r & 255;
    const int n0 = (rr & 15) * 64, k0 = (rr >> 4) * 64;
    const float* W = (z == 0) ? W0 : (z == 1) ? W1 : (z == 2) ? W2 : W3;
    const size_t zoff = (size_t)z * DMODEL * DMODEL;
#pragma unroll
    for (int it = 0; it < 4; ++it) {
        int idx = tid + it * 256;
        int rw = idx >> 4;
        int c4 = (idx & 15) * 4;
        float4 v = *reinterpret_cast<const float4*>(&W[(size_t)(k0 + rw) * DMODEL + n0 + c4]);
        L[rw][c4 + 0] = v.x; L[rw][c4 + 1] = v.y; L[rw][c4 + 2] = v.z; L[rw][c4 + 3] = v.w;
    }
    __syncthreads();
    int rn = tid >> 2;
    int ks = (tid & 3) * 16;
#pragma unroll
    for (int g = 0; g < 4; ++g) {
        ushort4 h;
        h.x = f2bf(L[ks + g * 4 + 0][rn]);
        h.y = f2bf(L[ks + g * 4 + 1][rn]);
        h.z = f2bf(L[ks + g * 4 + 2][rn]);
        h.w = f2bf(L[ks + g * 4 + 3][rn]);
        size_t o = zoff + (size_t)(n0 + rn) * DMODEL + k0 + ks + g * 4;
        *reinterpret_cast<ushort4*>(&Th[o]) = h;
    }
}

// ---------------------------------------------------------------------------
// Fused QKV GEMM, A-tile reuse (r15 proven version).
// ---------------------------------------------------------------------------
__global__ __launch_bounds__(256) void k_mgemm_qkv(const unsigned short* __restrict__ Ah_g,
                                                   const unsigned short* __restrict__ Wp,
                                                   const float* __restrict__ bq,
                                                   const float* __restrict__ bk,
                                                   const float* __restrict__ bv,
                                                   unsigned short* __restrict__ qh_,
                                                   unsigned short* __restrict__ kh_,
                                                   unsigned short* __restrict__ vth,
                                                   const float* __restrict__ sin_t,
                                                   const float* __restrict__ cos_t) {
    __shared__ unsigned short Ah[2][128 * 64];
    __shared__ unsigned short Bh[2][3][64 * 64];
    const int tid = threadIdx.x;
    const int lane = tid & 63;
    const int w = tid >> 6;

    int bid = blockIdx.x;
    int wg = (bid & 7) * 64 + (bid >> 3);
    const int m0 = (wg >> 4) * 128;
    const int n0 = (wg & 15) * 64;
    const size_t WE = (size_t)DMODEL * DMODEL;

    size_t a_goff[4]; int a_ldst[4];
#pragma unroll
    for (int it = 0; it < 4; ++it) {
        int off = it * 4096 + w * 1024 + lane * 16;
        int row = off >> 7;
        int pg = (off >> 4) & 7;
        int lg = pg ^ (row & 7);
        a_goff[it] = (size_t)(m0 + row) * DMODEL + lg * 8;
        a_ldst[it] = it * 2048 + w * 512;
    }
    size_t b_goff[2]; int b_ldst[2];
#pragma unroll
    for (int it = 0; it < 2; ++it) {
        int off = it * 4096 + w * 1024 + lane * 16;
        int row = off >> 7;
        int pg = (off >> 4) & 7;
        int lg = pg ^ (row & 7);
        b_goff[it] = (size_t)(n0 + row) * DMODEL + lg * 8;
        b_ldst[it] = it * 2048 + w * 512;
    }

    int aoff[2][2], boff[4][2];
#pragma unroll
    for (int mf = 0; mf < 2; ++mf)
#pragma unroll
        for (int ks = 0; ks < 2; ++ks) {
            int row = w * 32 + mf * 16 + (lane & 15);
            int g = ks * 4 + (lane >> 4);
            aoff[mf][ks] = row * 64 + ((g ^ (row & 7)) * 8);
        }
#pragma unroll
    for (int nf = 0; nf < 4; ++nf)
#pragma unroll
        for (int ks = 0; ks < 2; ++ks) {
            int row = nf * 16 + (lane & 15);
            int g = ks * 4 + (lane >> 4);
            boff[nf][ks] = row * 64 + ((g ^ (row & 7)) * 8);
        }

    f32x4 acc[3][2][4];
#pragma unroll
    for (int z = 0; z < 3; ++z)
#pragma unroll
        for (int mf = 0; mf < 2; ++mf)
#pragma unroll
            for (int nf = 0; nf < 4; ++nf) acc[z][mf][nf] = (f32x4){0.f, 0.f, 0.f, 0.f};

#define STAGEG(BUF, KT) do {                                                  \
        int k0_ = (KT) * 64;                                                  \
        gl2lds16(Ah_g + a_goff[0] + k0_, &Ah[BUF][a_ldst[0]]);                \
        gl2lds16(Ah_g + a_goff[1] + k0_, &Ah[BUF][a_ldst[1]]);                \
        gl2lds16(Ah_g + a_goff[2] + k0_, &Ah[BUF][a_ldst[2]]);                \
        gl2lds16(Ah_g + a_goff[3] + k0_, &Ah[BUF][a_ldst[3]]);                \
        gl2lds16(Wp + 0 * WE + b_goff[0] + k0_, &Bh[BUF][0][b_ldst[0]]);      \
        gl2lds16(Wp + 0 * WE + b_goff[1] + k0_, &Bh[BUF][0][b_ldst[1]]);      \
        gl2lds16(Wp + 1 * WE + b_goff[0] + k0_, &Bh[BUF][1][b_ldst[0]]);      \
        gl2lds16(Wp + 1 * WE + b_goff[1] + k0_, &Bh[BUF][1][b_ldst[1]]);      \
        gl2lds16(Wp + 2 * WE + b_goff[0] + k0_, &Bh[BUF][2][b_ldst[0]]);      \
        gl2lds16(Wp + 2 * WE + b_goff[1] + k0_, &Bh[BUF][2][b_ldst[1]]);      \
    } while (0)

    STAGEG(0, 0);

    for (int kt = 0; kt < 16; ++kt) {
        const int cur = kt & 1;
        asm volatile("s_waitcnt vmcnt(0)" ::: "memory");
        __builtin_amdgcn_s_barrier();
        if (kt < 15) STAGEG(cur ^ 1, kt + 1);
#pragma unroll
        for (int ks = 0; ks < 2; ++ks) {
            bf16x8 ah[2];
#pragma unroll
            for (int mf = 0; mf < 2; ++mf)
                ah[mf] = *reinterpret_cast<const bf16x8*>(&Ah[cur][aoff[mf][ks]]);
#pragma unroll
            for (int z = 0; z < 3; ++z) {
                bf16x8 bh[4];
#pragma unroll
                for (int nf = 0; nf < 4; ++nf)
                    bh[nf] = *reinterpret_cast<const bf16x8*>(&Bh[cur][z][boff[nf][ks]]);
#pragma unroll
                for (int mf = 0; mf < 2; ++mf)
#pragma unroll
                    for (int nf = 0; nf < 4; ++nf)
                        acc[z][mf][nf] = __builtin_amdgcn_mfma_f32_16x16x32_bf16(ah[mf], bh[nf], acc[z][mf][nf], 0, 0, 0);
            }
        }
    }
#undef STAGEG

    const int c = lane & 15;
    const int rq = lane >> 4;
    float bvq[4], bvk[4], bvv[4];
#pragma unroll
    for (int nf = 0; nf < 4; ++nf) {
        bvq[nf] = bq[n0 + nf * 16 + c];
        bvk[nf] = bk[n0 + nf * 16 + c];
        bvv[nf] = bv[n0 + nf * 16 + c];
    }

#pragma unroll
    for (int mf = 0; mf < 2; ++mf) {
        int mbase = m0 + w * 32 + mf * 16 + rq * 4;
#pragma unroll
        for (int z = 0; z < 2; ++z) {
            const float* bb_ = (z == 0) ? bvq : bvk;
            unsigned short* Ohi = (z == 0) ? qh_ : kh_;
#pragma unroll
            for (int r2 = 0; r2 < 4; ++r2) {
                int m = mbase + r2;
                int srow = m & (SEQ - 1);
                float x0 = acc[z][mf][0][r2] + bb_[0];
                float x1 = acc[z][mf][1][r2] + bb_[1];
                float x2 = acc[z][mf][2][r2] + bb_[2];
                float x3 = acc[z][mf][3][r2] + bb_[3];
                float s0 = sin_t[srow * 32 + c],      c0 = cos_t[srow * 32 + c];
                float s1 = sin_t[srow * 32 + 16 + c], c1 = cos_t[srow * 32 + 16 + c];
                float o0 = c0 * x0 - s0 * x2;
                float o2 = s0 * x0 + c0 * x2;
                float o1 = c1 * x1 - s1 * x3;
                float o3 = s1 * x1 + c1 * x3;
                if (z == 0) {
                    const float qs = 0.18033688011112042f;   // 0.125*log2(e)
                    o0 *= qs; o1 *= qs; o2 *= qs; o3 *= qs;
                }
                float ov[4] = { o0, o1, o2, o3 };
                size_t base = (size_t)m * DMODEL + n0 + c;
#pragma unroll
                for (int nf = 0; nf < 4; ++nf)
                    Ohi[base + nf * 16] = f2bf(ov[nf]);
            }
        }
        {
            int bb = mbase >> 11;
            int s = mbase & (SEQ - 1);
            int h = n0 >> 6;
#pragma unroll
            for (int nf = 0; nf < 4; ++nf) {
                ushort4 h4;
                float v0 = acc[2][mf][nf][0] + bvv[nf];
                float v1 = acc[2][mf][nf][1] + bvv[nf];
                float v2 = acc[2][mf][nf][2] + bvv[nf];
                float v3 = acc[2][mf][nf][3] + bvv[nf];
                h4.x = f2bf(v0); h4.y = f2bf(v1); h4.z = f2bf(v2); h4.w = f2bf(v3);
                int d = nf * 16 + c;
                size_t o = ((size_t)((bb * NH + h) * KD + d)) * SEQ + s;
                *reinterpret_cast<ushort4*>(&vth[o]) = h4;
            }
        }
    }
}

// ---------------------------------------------------------------------------
// O-projection GEMM (r15 proven version).
// ---------------------------------------------------------------------------
__global__ __launch_bounds__(256) void k_mgemm_o(const unsigned short* __restrict__ Ah_g,
                                                 const unsigned short* __restrict__ Bh_g,
                                                 const float* __restrict__ bias,
                                                 float* __restrict__ Cf) {
    __shared__ unsigned short Ah[2][128 * 64];
    __shared__ unsigned short Bh[2][64 * 64];
    const int tid = threadIdx.x;
    const int lane = tid & 63;
    const int w = tid >> 6;

    int bid = blockIdx.x;
    int wg = (bid & 7) * 64 + (bid >> 3);
    const int m0 = (wg >> 4) * 128;
    const int n0 = (wg & 15) * 64;

    size_t a_goff[4]; int a_ldst[4];
#pragma unroll
    for (int it = 0; it < 4; ++it) {
        int off = it * 4096 + w * 1024 + lane * 16;
        int row = off >> 7;
        int pg = (off >> 4) & 7;
        int lg = pg ^ (row & 7);
        a_goff[it] = (size_t)(m0 + row) * DMODEL + lg * 8;
        a_ldst[it] = it * 2048 + w * 512;
    }
    size_t b_goff[2]; int b_ldst[2];
#pragma unroll
    for (int it = 0; it < 2; ++it) {
        int off = it * 4096 + w * 1024 + lane * 16;
        int row = off >> 7;
        int pg = (off >> 4) & 7;
        int lg = pg ^ (row & 7);
        b_goff[it] = (size_t)(n0 + row) * DMODEL + lg * 8;
        b_ldst[it] = it * 2048 + w * 512;
    }

    int aoff[2][2], boff[4][2];
#pragma unroll
    for (int mf = 0; mf < 2; ++mf)
#pragma unroll
        for (int ks = 0; ks < 2; ++ks) {
            int row = w * 32 + mf * 16 + (lane & 15);
            int g = ks * 4 + (lane >> 4);
            aoff[mf][ks] = row * 64 + ((g ^ (row & 7)) * 8);
        }
#pragma unroll
    for (int nf = 0; nf < 4; ++nf)
#pragma unroll
        for (int ks = 0; ks < 2; ++ks) {
            int row = nf * 16 + (lane & 15);
            int g = ks * 4 + (lane >> 4);
            boff[nf][ks] = row * 64 + ((g ^ (row & 7)) * 8);
        }

    f32x4 acc[2][4];
#pragma unroll
    for (int mf = 0; mf < 2; ++mf)
#pragma unroll
        for (int nf = 0; nf < 4; ++nf) acc[mf][nf] = (f32x4){0.f, 0.f, 0.f, 0.f};

#define STAGEG(BUF, KT) do {                                                  \
        int k0_ = (KT) * 64;                                                  \
        gl2lds16(Ah_g + a_goff[0] + k0_, &Ah[BUF][a_ldst[0]]);                \
        gl2lds16(Ah_g + a_goff[1] + k0_, &Ah[BUF][a_ldst[1]]);                \
        gl2lds16(Ah_g + a_goff[2] + k0_, &Ah[BUF][a_ldst[2]]);                \
        gl2lds16(Ah_g + a_goff[3] + k0_, &Ah[BUF][a_ldst[3]]);                \
        gl2lds16(Bh_g + b_goff[0] + k0_, &Bh[BUF][b_ldst[0]]);                \
        gl2lds16(Bh_g + b_goff[1] + k0_, &Bh[BUF][b_ldst[1]]);                \
    } while (0)

    STAGEG(0, 0);

    for (int kt = 0; kt < 16; ++kt) {
        const int cur = kt & 1;
        asm volatile("s_waitcnt vmcnt(0)" ::: "memory");
        __builtin_amdgcn_s_barrier();
        if (kt < 15) STAGEG(cur ^ 1, kt + 1);
#pragma unroll
        for (int ks = 0; ks < 2; ++ks) {
            bf16x8 ah[2], bh[4];
#pragma unroll
            for (int mf = 0; mf < 2; ++mf)
                ah[mf] = *reinterpret_cast<const bf16x8*>(&Ah[cur][aoff[mf][ks]]);
#pragma unroll
            for (int nf = 0; nf < 4; ++nf)
                bh[nf] = *reinterpret_cast<const bf16x8*>(&Bh[cur][boff[nf][ks]]);
#pragma unroll
            for (int mf = 0; mf < 2; ++mf)
#pragma unroll
                for (int nf = 0; nf < 4; ++nf)
                    acc[mf][nf] = __builtin_amdgcn_mfma_f32_16x16x32_bf16(ah[mf], bh[nf], acc[mf][nf], 0, 0, 0);
        }
    }
#undef STAGEG

    const int c = lane & 15;
    const int rq = lane >> 4;
    float bv[4];
#pragma unroll
    for (int nf = 0; nf < 4; ++nf) bv[nf] = bias[n0 + nf * 16 + c];
#pragma unroll
    for (int mf = 0; mf < 2; ++mf) {
        int mbase = m0 + w * 32 + mf * 16 + rq * 4;
#pragma unroll
        for (int nf = 0; nf < 4; ++nf)
#pragma unroll
            for (int r = 0; r < 4; ++r)
                Cf[(size_t)(mbase + r) * DMODEL + n0 + nf * 16 + c] = acc[mf][nf][r] + bv[nf];
    }
}

// ---------------------------------------------------------------------------
// Flash attention, split-T (2 splits x 16 KV-tiles). 32x32 MFMA, in-register
// P, K dbuf + V ring, deferred PV, 1 barrier/tile. Unnormalized softmax:
// partials are EXACTLY additive (acc, l) -> combine kernel.
// 1024 blocks = [split][b][h][qt], XCD-chunked. LDS 40KB -> 4 blocks/CU.
// ---------------------------------------------------------------------------
__global__ __launch_bounds__(256) void k_attn(const unsigned short* __restrict__ qhi,
                                              const unsigned short* __restrict__ khi,
                                              const unsigned short* __restrict__ vthi,
                                              float* __restrict__ accf,
                                              float* __restrict__ lsum) {
    __shared__ unsigned short Kh[2][64 * 64];
    __shared__ unsigned short Vh[3][64 * 64];   // [d][t], ring

    const int tid  = threadIdx.x;
    const int lane = tid & 63;
    const int w    = tid >> 6;

    int bid = blockIdx.x;
    int wg  = (bid & 7) * 128 + (bid >> 3);     // 1024 blocks, 8 XCD chunks
    const int qt = wg & 15;
    const int h  = (wg >> 4) & 15;
    const int b  = (wg >> 8) & 1;
    const int sp = wg >> 9;                      // t-split 0/1
    const int q0 = qt * 128;
    const int t_begin = sp * 16;

    const int l31 = lane & 31;
    const int lh  = lane >> 5;

    bf16x8 qf[4];
#pragma unroll
    for (int ks = 0; ks < 4; ++ks) {
        int row = q0 + w * 32 + l31;
        qf[ks] = *reinterpret_cast<const bf16x8*>(
            qhi + ((size_t)(b * SEQ + row) * NH + h) * KD + ks * 16 + lh * 8);
    }

    size_t gK[2], gV[2]; int ld_[2];
#pragma unroll
    for (int it = 0; it < 2; ++it) {
        int off = it * 4096 + tid * 16;
        int row = off >> 7;
        int pg = (off >> 4) & 7;
        int lg = pg ^ (row & 7);
        gK[it] = ((size_t)(b * SEQ + row) * NH + h) * KD + lg * 8;
        gV[it] = ((size_t)(b * NH + h) * KD + row) * SEQ + lg * 8;
        ld_[it] = it * 2048 + w * 512;
    }

    int foff[2][4];
#pragma unroll
    for (int tb = 0; tb < 2; ++tb)
#pragma unroll
        for (int ks = 0; ks < 4; ++ks)
            foff[tb][ks] = (tb * 32 + l31) * 64 + (((ks * 2 + lh) ^ (lane & 7)) * 8);

    f32x16 acc[2];
#pragma unroll
    for (int db = 0; db < 2; ++db)
#pragma unroll
        for (int r = 0; r < 16; ++r) acc[db][r] = 0.f;
    float l_part = 0.f;

    unsigned paw[4][4];
    union U8 { unsigned u[4]; bf16x8 v; };

#define STAGE(KB, VB, TT) do {                                               \
        size_t kadv = (size_t)(TT) * 64 * NH * KD;                           \
        size_t vadv = (size_t)(TT) * 64;                                     \
        gl2lds16(khi  + gK[0] + kadv, &Kh[KB][ld_[0]]);                      \
        gl2lds16(khi  + gK[1] + kadv, &Kh[KB][ld_[1]]);                      \
        gl2lds16(vthi + gV[0] + vadv, &Vh[VB][ld_[0]]);                      \
        gl2lds16(vthi + gV[1] + vadv, &Vh[VB][ld_[1]]);                      \
    } while (0)

#define PV_STEP(VSRC) do {                                                   \
        _Pragma("unroll")                                                    \
        for (int db = 0; db < 2; ++db) {                                     \
            _Pragma("unroll")                                                \
            for (int ks = 0; ks < 4; ++ks) {                                 \
                bf16x8 vf = *reinterpret_cast<const bf16x8*>(&Vh[VSRC][foff[db][ks]]); \
                U8 pa; pa.u[0] = paw[ks][0]; pa.u[1] = paw[ks][1];           \
                pa.u[2] = paw[ks][2]; pa.u[3] = paw[ks][3];                  \
                acc[db] = __builtin_amdgcn_mfma_f32_32x32x16_bf16(pa.v, vf, acc[db], 0, 0, 0); \
            }                                                                \
        }                                                                    \
    } while (0)

    STAGE(0, 0, t_begin);

    int vnext = 1;
    int vprev = 2;

    for (int ti = 0; ti < 16; ++ti) {
        const int t = t_begin + ti;
        const int ck = ti & 1;
        asm volatile("s_waitcnt vmcnt(0)" ::: "memory");
        __builtin_amdgcn_s_barrier();
        if (ti < 15) STAGE(ck ^ 1, vnext, t + 1);

        __builtin_amdgcn_s_setprio(1);
        f32x16 s[2];
#pragma unroll
        for (int tb = 0; tb < 2; ++tb) {
#pragma unroll
            for (int r = 0; r < 16; ++r) s[tb][r] = 0.f;
#pragma unroll
            for (int ks = 0; ks < 4; ++ks) {
                bf16x8 kf = *reinterpret_cast<const bf16x8*>(&Kh[ck][foff[tb][ks]]);
                s[tb] = __builtin_amdgcn_mfma_f32_32x32x16_bf16(kf, qf[ks], s[tb], 0, 0, 0);
            }
        }
        if (ti > 0) PV_STEP(vprev);
        __builtin_amdgcn_s_setprio(0);

#pragma unroll
        for (int tb = 0; tb < 2; ++tb) {
            float e[16];
#pragma unroll
            for (int r = 0; r < 16; ++r) {
                e[r] = exp2_hw(s[tb][r]);
                l_part += e[r];
            }
#pragma unroll
            for (int half = 0; half < 2; ++half) {
                unsigned pk01 = cvt_pk_bf16(e[half * 8 + 0], e[half * 8 + 1]);
                unsigned pk23 = cvt_pk_bf16(e[half * 8 + 2], e[half * 8 + 3]);
                unsigned pk45 = cvt_pk_bf16(e[half * 8 + 4], e[half * 8 + 5]);
                unsigned pk67 = cvt_pk_bf16(e[half * 8 + 6], e[half * 8 + 7]);
                asm volatile("v_permlane32_swap_b32 %0, %1" : "+v"(pk01), "+v"(pk45));
                asm volatile("v_permlane32_swap_b32 %0, %1" : "+v"(pk23), "+v"(pk67));
                paw[tb * 2 + half][0] = pk01;
                paw[tb * 2 + half][1] = pk23;
                paw[tb * 2 + half][2] = pk45;
                paw[tb * 2 + half][3] = pk67;
            }
        }

        vnext = (vnext == 2) ? 0 : vnext + 1;
        vprev = (vprev == 2) ? 0 : vprev + 1;
    }

    PV_STEP(vprev);
#undef PV_STEP
#undef STAGE

    // ---- store partials: l (once per q row), fp32 acc ----
    l_part += __shfl_xor(l_part, 32);
    float* accp = accf + (size_t)sp * MROWS * DMODEL;
    if (lh == 0) {
        int qg = q0 + w * 32 + l31;
        lsum[(size_t)sp * (MROWS * NH) + (size_t)(b * SEQ + qg) * NH + h] = l_part;
    }
#pragma unroll
    for (int db = 0; db < 2; ++db) {
#pragma unroll
        for (int r = 0; r < 16; ++r) {
            int q = (r & 3) + 8 * (r >> 2) + 4 * lh;
            int qg = q0 + w * 32 + q;
            int d = db * 32 + l31;
            accp[((size_t)(b * SEQ + qg) * NH + h) * KD + d] = acc[db][r];
        }
    }
}

// ---------------------------------------------------------------------------
// Combine: ctx = (acc0 + acc1) / (l0 + l1) -> bf16. 8 elems/thread.
// ---------------------------------------------------------------------------
__global__ __launch_bounds__(256) void k_comb(const float* __restrict__ accf,
                                              const float* __restrict__ lsum,
                                              unsigned short* __restrict__ ch) {
    int idx = blockIdx.x * 256 + threadIdx.x;     // 0..524287
    size_t o = (size_t)idx * 8;
    int rI = (int)(o >> 6);                        // (b*SEQ+s)*NH+h
    float inv = 1.0f / (lsum[rI] + lsum[MROWS * NH + rI]);
    const float* a0 = accf;
    const float* a1 = accf + (size_t)MROWS * DMODEL;
    float4 x0 = *reinterpret_cast<const float4*>(a0 + o);
    float4 x1 = *reinterpret_cast<const float4*>(a0 + o + 4);
    float4 y0 = *reinterpret_cast<const float4*>(a1 + o);
    float4 y1 = *reinterpret_cast<const float4*>(a1 + o + 4);
    ushort4 h0, h1;
    h0.x = f2bf((x0.x + y0.x) * inv);
    h0.y = f2bf((x0.y + y0.y) * inv);
    h0.z = f2bf((x0.z + y0.z) * inv);
    h0.w = f2bf((x0.w + y0.w) * inv);
    h1.x = f2bf((x1.x + y1.x) * inv);
    h1.y = f2bf((x1.y + y1.y) * inv);
    h1.z = f2bf((x1.z + y1.z) * inv);
    h1.w = f2bf((x1.w + y1.w) * inv);
    *reinterpret_cast<ushort4*>(ch + o) = h0;
    *reinterpret_cast<ushort4*>(ch + o + 4) = h1;
}

// ---------------------------------------------------------------------------
extern "C" void kernel_launch(void* const* d_in, const int* in_sizes, int n_in,
                              void* d_out, int out_size, void* d_ws, size_t ws_size,
                              hipStream_t stream) {
    const float* x  = (const float*)d_in[0];
    const float* Wq = (const float*)d_in[1];
    const float* bq = (const float*)d_in[2];
    const float* Wk = (const float*)d_in[3];
    const float* bk = (const float*)d_in[4];
    const float* Wv = (const float*)d_in[5];
    const float* bv = (const float*)d_in[6];
    const float* Wo = (const float*)d_in[7];
    const float* bo = (const float*)d_in[8];
    float* out = (float*)d_out;

    const size_t NE = (size_t)MROWS * DMODEL;   // 4M
    const size_t WE = (size_t)DMODEL * DMODEL;  // 1M
    float* ws    = (float*)d_ws;
    float* sin_t = ws;
    float* cos_t = sin_t + SEQ * 32;
    unsigned short* p = (unsigned short*)(cos_t + SEQ * 32);
    unsigned short* xh   = p; p += NE;
    unsigned short* qh_  = p; p += NE;
    unsigned short* kh_  = p; p += NE;
    unsigned short* vth  = p; p += NE;
    unsigned short* wth  = p; p += 4 * WE;   // hi pool: [Wq|Wk|Wv|Wo]^T
    float* accf = (float*)p;                  // 2 x NE fp32
    float* lsum = accf + 2 * NE;              // 2 x MROWS*NH fp32
    unsigned short* ctxh = xh;                // alias: x dead after V projection

    k_prep<<<5376, 256, 0, stream>>>(x, Wq, Wk, Wv, Wo, sin_t, cos_t, xh, wth);

    k_mgemm_qkv<<<512, 256, 0, stream>>>(xh, wth, bq, bk, bv, qh_, kh_, vth, sin_t, cos_t);

    k_attn<<<1024, 256, 0, stream>>>(qh_, kh_, vth, accf, lsum);

    k_comb<<<(int)(NE / 8 / 256), 256, 0, stream>>>(accf, lsum, ctxh);

    k_mgemm_o<<<512, 256, 0, stream>>>(ctxh, wth + 3 * WE, bo, out);
}

// Round 18
// 109.789 us; speedup vs baseline: 1.1239x; 1.1239x over previous
//
#include <hip/hip_runtime.h>
#include <math.h>

#define NH 16
#define KD 64
#define DMODEL 1024
#define BATCH 2
#define SEQ 2048
#define MROWS (BATCH*SEQ)

typedef float f32x4 __attribute__((ext_vector_type(4)));
typedef float f32x16 __attribute__((ext_vector_type(16)));
typedef __bf16 bf16x8 __attribute__((ext_vector_type(8)));

__device__ __forceinline__ unsigned short f2bf(float x) {
    union { float f; unsigned u; } a; a.f = x;
    unsigned r = a.u + 0x7fffu + ((a.u >> 16) & 1u);
    return (unsigned short)(r >> 16);
}
__device__ __forceinline__ unsigned cvt_pk_bf16(float lo, float hi) {
    unsigned r;
    asm("v_cvt_pk_bf16_f32 %0, %1, %2" : "=v"(r) : "v"(lo), "v"(hi));
    return r;
}
__device__ __forceinline__ float exp2_hw(float x) {
    float r;
    asm("v_exp_f32 %0, %1" : "=v"(r) : "v"(x));
    return r;
}

__device__ __forceinline__ void gl2lds16(const void* gsrc, void* ldst) {
    __builtin_amdgcn_global_load_lds(
        (const __attribute__((address_space(1))) void*)gsrc,
        (__attribute__((address_space(3))) void*)ldst, 16, 0, 0);
}

// ---------------------------------------------------------------------------
// Fused prep: [0,256) rope tables; [256,4352) cvt_x; [4352,5376) cvt_w4.
// ---------------------------------------------------------------------------
__global__ __launch_bounds__(256) void k_prep(const float* __restrict__ x,
                                              const float* __restrict__ W0,
                                              const float* __restrict__ W1,
                                              const float* __restrict__ W2,
                                              const float* __restrict__ W3,
                                              float* __restrict__ sin_t,
                                              float* __restrict__ cos_t,
                                              unsigned short* __restrict__ xh,
                                              unsigned short* __restrict__ Th) {
    __shared__ float L[64][65];
    const int bid = blockIdx.x;
    const int tid = threadIdx.x;
    if (bid < 256) {
        int idx = bid * 256 + tid;
        int s = idx >> 5, i = idx & 31;
        float invf = expf((float)(2 * i) * (-logf(10000.0f) / (float)KD));
        float ang = (float)s * invf;
        sin_t[idx] = sinf(ang);
        cos_t[idx] = cosf(ang);
        return;
    }
    if (bid < 4352) {
        int idx = (bid - 256) * 256 + tid;
        float4 v = reinterpret_cast<const float4*>(x)[idx];
        ushort4 h;
        h.x = f2bf(v.x); h.y = f2bf(v.y); h.z = f2bf(v.z); h.w = f2bf(v.w);
        reinterpret_cast<ushort4*>(xh)[idx] = h;
        return;
    }
    int r = bid - 4352;
    int z = r >> 8;
    int rr = r & 255;
    const int n0 = (rr & 15) * 64, k0 = (rr >> 4) * 64;
    const float* W = (z == 0) ? W0 : (z == 1) ? W1 : (z == 2) ? W2 : W3;
    const size_t zoff = (size_t)z * DMODEL * DMODEL;
#pragma unroll
    for (int it = 0; it < 4; ++it) {
        int idx = tid + it * 256;
        int rw = idx >> 4;
        int c4 = (idx & 15) * 4;
        float4 v = *reinterpret_cast<const float4*>(&W[(size_t)(k0 + rw) * DMODEL + n0 + c4]);
        L[rw][c4 + 0] = v.x; L[rw][c4 + 1] = v.y; L[rw][c4 + 2] = v.z; L[rw][c4 + 3] = v.w;
    }
    __syncthreads();
    int rn = tid >> 2;
    int ks = (tid & 3) * 16;
#pragma unroll
    for (int g = 0; g < 4; ++g) {
        ushort4 h;
        h.x = f2bf(L[ks + g * 4 + 0][rn]);
        h.y = f2bf(L[ks + g * 4 + 1][rn]);
        h.z = f2bf(L[ks + g * 4 + 2][rn]);
        h.w = f2bf(L[ks + g * 4 + 3][rn]);
        size_t o = zoff + (size_t)(n0 + rn) * DMODEL + k0 + ks + g * 4;
        *reinterpret_cast<ushort4*>(&Th[o]) = h;
    }
}

// ---------------------------------------------------------------------------
// Fused QKV GEMM, A-tile reuse (r15 proven version).
// ---------------------------------------------------------------------------
__global__ __launch_bounds__(256) void k_mgemm_qkv(const unsigned short* __restrict__ Ah_g,
                                                   const unsigned short* __restrict__ Wp,
                                                   const float* __restrict__ bq,
                                                   const float* __restrict__ bk,
                                                   const float* __restrict__ bv,
                                                   unsigned short* __restrict__ qh_,
                                                   unsigned short* __restrict__ kh_,
                                                   unsigned short* __restrict__ vth,
                                                   const float* __restrict__ sin_t,
                                                   const float* __restrict__ cos_t) {
    __shared__ unsigned short Ah[2][128 * 64];
    __shared__ unsigned short Bh[2][3][64 * 64];
    const int tid = threadIdx.x;
    const int lane = tid & 63;
    const int w = tid >> 6;

    int bid = blockIdx.x;
    int wg = (bid & 7) * 64 + (bid >> 3);
    const int m0 = (wg >> 4) * 128;
    const int n0 = (wg & 15) * 64;
    const size_t WE = (size_t)DMODEL * DMODEL;

    size_t a_goff[4]; int a_ldst[4];
#pragma unroll
    for (int it = 0; it < 4; ++it) {
        int off = it * 4096 + w * 1024 + lane * 16;
        int row = off >> 7;
        int pg = (off >> 4) & 7;
        int lg = pg ^ (row & 7);
        a_goff[it] = (size_t)(m0 + row) * DMODEL + lg * 8;
        a_ldst[it] = it * 2048 + w * 512;
    }
    size_t b_goff[2]; int b_ldst[2];
#pragma unroll
    for (int it = 0; it < 2; ++it) {
        int off = it * 4096 + w * 1024 + lane * 16;
        int row = off >> 7;
        int pg = (off >> 4) & 7;
        int lg = pg ^ (row & 7);
        b_goff[it] = (size_t)(n0 + row) * DMODEL + lg * 8;
        b_ldst[it] = it * 2048 + w * 512;
    }

    int aoff[2][2], boff[4][2];
#pragma unroll
    for (int mf = 0; mf < 2; ++mf)
#pragma unroll
        for (int ks = 0; ks < 2; ++ks) {
            int row = w * 32 + mf * 16 + (lane & 15);
            int g = ks * 4 + (lane >> 4);
            aoff[mf][ks] = row * 64 + ((g ^ (row & 7)) * 8);
        }
#pragma unroll
    for (int nf = 0; nf < 4; ++nf)
#pragma unroll
        for (int ks = 0; ks < 2; ++ks) {
            int row = nf * 16 + (lane & 15);
            int g = ks * 4 + (lane >> 4);
            boff[nf][ks] = row * 64 + ((g ^ (row & 7)) * 8);
        }

    f32x4 acc[3][2][4];
#pragma unroll
    for (int z = 0; z < 3; ++z)
#pragma unroll
        for (int mf = 0; mf < 2; ++mf)
#pragma unroll
            for (int nf = 0; nf < 4; ++nf) acc[z][mf][nf] = (f32x4){0.f, 0.f, 0.f, 0.f};

#define STAGEG(BUF, KT) do {                                                  \
        int k0_ = (KT) * 64;                                                  \
        gl2lds16(Ah_g + a_goff[0] + k0_, &Ah[BUF][a_ldst[0]]);                \
        gl2lds16(Ah_g + a_goff[1] + k0_, &Ah[BUF][a_ldst[1]]);                \
        gl2lds16(Ah_g + a_goff[2] + k0_, &Ah[BUF][a_ldst[2]]);                \
        gl2lds16(Ah_g + a_goff[3] + k0_, &Ah[BUF][a_ldst[3]]);                \
        gl2lds16(Wp + 0 * WE + b_goff[0] + k0_, &Bh[BUF][0][b_ldst[0]]);      \
        gl2lds16(Wp + 0 * WE + b_goff[1] + k0_, &Bh[BUF][0][b_ldst[1]]);      \
        gl2lds16(Wp + 1 * WE + b_goff[0] + k0_, &Bh[BUF][1][b_ldst[0]]);      \
        gl2lds16(Wp + 1 * WE + b_goff[1] + k0_, &Bh[BUF][1][b_ldst[1]]);      \
        gl2lds16(Wp + 2 * WE + b_goff[0] + k0_, &Bh[BUF][2][b_ldst[0]]);      \
        gl2lds16(Wp + 2 * WE + b_goff[1] + k0_, &Bh[BUF][2][b_ldst[1]]);      \
    } while (0)

    STAGEG(0, 0);

    for (int kt = 0; kt < 16; ++kt) {
        const int cur = kt & 1;
        asm volatile("s_waitcnt vmcnt(0)" ::: "memory");
        __builtin_amdgcn_s_barrier();
        if (kt < 15) STAGEG(cur ^ 1, kt + 1);
#pragma unroll
        for (int ks = 0; ks < 2; ++ks) {
            bf16x8 ah[2];
#pragma unroll
            for (int mf = 0; mf < 2; ++mf)
                ah[mf] = *reinterpret_cast<const bf16x8*>(&Ah[cur][aoff[mf][ks]]);
#pragma unroll
            for (int z = 0; z < 3; ++z) {
                bf16x8 bh[4];
#pragma unroll
                for (int nf = 0; nf < 4; ++nf)
                    bh[nf] = *reinterpret_cast<const bf16x8*>(&Bh[cur][z][boff[nf][ks]]);
#pragma unroll
                for (int mf = 0; mf < 2; ++mf)
#pragma unroll
                    for (int nf = 0; nf < 4; ++nf)
                        acc[z][mf][nf] = __builtin_amdgcn_mfma_f32_16x16x32_bf16(ah[mf], bh[nf], acc[z][mf][nf], 0, 0, 0);
            }
        }
    }
#undef STAGEG

    const int c = lane & 15;
    const int rq = lane >> 4;
    float bvq[4], bvk[4], bvv[4];
#pragma unroll
    for (int nf = 0; nf < 4; ++nf) {
        bvq[nf] = bq[n0 + nf * 16 + c];
        bvk[nf] = bk[n0 + nf * 16 + c];
        bvv[nf] = bv[n0 + nf * 16 + c];
    }

#pragma unroll
    for (int mf = 0; mf < 2; ++mf) {
        int mbase = m0 + w * 32 + mf * 16 + rq * 4;
#pragma unroll
        for (int z = 0; z < 2; ++z) {
            const float* bb_ = (z == 0) ? bvq : bvk;
            unsigned short* Ohi = (z == 0) ? qh_ : kh_;
#pragma unroll
            for (int r2 = 0; r2 < 4; ++r2) {
                int m = mbase + r2;
                int srow = m & (SEQ - 1);
                float x0 = acc[z][mf][0][r2] + bb_[0];
                float x1 = acc[z][mf][1][r2] + bb_[1];
                float x2 = acc[z][mf][2][r2] + bb_[2];
                float x3 = acc[z][mf][3][r2] + bb_[3];
                float s0 = sin_t[srow * 32 + c],      c0 = cos_t[srow * 32 + c];
                float s1 = sin_t[srow * 32 + 16 + c], c1 = cos_t[srow * 32 + 16 + c];
                float o0 = c0 * x0 - s0 * x2;
                float o2 = s0 * x0 + c0 * x2;
                float o1 = c1 * x1 - s1 * x3;
                float o3 = s1 * x1 + c1 * x3;
                if (z == 0) {
                    const float qs = 0.18033688011112042f;   // 0.125*log2(e)
                    o0 *= qs; o1 *= qs; o2 *= qs; o3 *= qs;
                }
                float ov[4] = { o0, o1, o2, o3 };
                size_t base = (size_t)m * DMODEL + n0 + c;
#pragma unroll
                for (int nf = 0; nf < 4; ++nf)
                    Ohi[base + nf * 16] = f2bf(ov[nf]);
            }
        }
        {
            int bb = mbase >> 11;
            int s = mbase & (SEQ - 1);
            int h = n0 >> 6;
#pragma unroll
            for (int nf = 0; nf < 4; ++nf) {
                ushort4 h4;
                float v0 = acc[2][mf][nf][0] + bvv[nf];
                float v1 = acc[2][mf][nf][1] + bvv[nf];
                float v2 = acc[2][mf][nf][2] + bvv[nf];
                float v3 = acc[2][mf][nf][3] + bvv[nf];
                h4.x = f2bf(v0); h4.y = f2bf(v1); h4.z = f2bf(v2); h4.w = f2bf(v3);
                int d = nf * 16 + c;
                size_t o = ((size_t)((bb * NH + h) * KD + d)) * SEQ + s;
                *reinterpret_cast<ushort4*>(&vth[o]) = h4;
            }
        }
    }
}

// ---------------------------------------------------------------------------
// O-projection GEMM (r15 proven version).
// ---------------------------------------------------------------------------
__global__ __launch_bounds__(256) void k_mgemm_o(const unsigned short* __restrict__ Ah_g,
                                                 const unsigned short* __restrict__ Bh_g,
                                                 const float* __restrict__ bias,
                                                 float* __restrict__ Cf) {
    __shared__ unsigned short Ah[2][128 * 64];
    __shared__ unsigned short Bh[2][64 * 64];
    const int tid = threadIdx.x;
    const int lane = tid & 63;
    const int w = tid >> 6;

    int bid = blockIdx.x;
    int wg = (bid & 7) * 64 + (bid >> 3);
    const int m0 = (wg >> 4) * 128;
    const int n0 = (wg & 15) * 64;

    size_t a_goff[4]; int a_ldst[4];
#pragma unroll
    for (int it = 0; it < 4; ++it) {
        int off = it * 4096 + w * 1024 + lane * 16;
        int row = off >> 7;
        int pg = (off >> 4) & 7;
        int lg = pg ^ (row & 7);
        a_goff[it] = (size_t)(m0 + row) * DMODEL + lg * 8;
        a_ldst[it] = it * 2048 + w * 512;
    }
    size_t b_goff[2]; int b_ldst[2];
#pragma unroll
    for (int it = 0; it < 2; ++it) {
        int off = it * 4096 + w * 1024 + lane * 16;
        int row = off >> 7;
        int pg = (off >> 4) & 7;
        int lg = pg ^ (row & 7);
        b_goff[it] = (size_t)(n0 + row) * DMODEL + lg * 8;
        b_ldst[it] = it * 2048 + w * 512;
    }

    int aoff[2][2], boff[4][2];
#pragma unroll
    for (int mf = 0; mf < 2; ++mf)
#pragma unroll
        for (int ks = 0; ks < 2; ++ks) {
            int row = w * 32 + mf * 16 + (lane & 15);
            int g = ks * 4 + (lane >> 4);
            aoff[mf][ks] = row * 64 + ((g ^ (row & 7)) * 8);
        }
#pragma unroll
    for (int nf = 0; nf < 4; ++nf)
#pragma unroll
        for (int ks = 0; ks < 2; ++ks) {
            int row = nf * 16 + (lane & 15);
            int g = ks * 4 + (lane >> 4);
            boff[nf][ks] = row * 64 + ((g ^ (row & 7)) * 8);
        }

    f32x4 acc[2][4];
#pragma unroll
    for (int mf = 0; mf < 2; ++mf)
#pragma unroll
        for (int nf = 0; nf < 4; ++nf) acc[mf][nf] = (f32x4){0.f, 0.f, 0.f, 0.f};

#define STAGEG(BUF, KT) do {                                                  \
        int k0_ = (KT) * 64;                                                  \
        gl2lds16(Ah_g + a_goff[0] + k0_, &Ah[BUF][a_ldst[0]]);                \
        gl2lds16(Ah_g + a_goff[1] + k0_, &Ah[BUF][a_ldst[1]]);                \
        gl2lds16(Ah_g + a_goff[2] + k0_, &Ah[BUF][a_ldst[2]]);                \
        gl2lds16(Ah_g + a_goff[3] + k0_, &Ah[BUF][a_ldst[3]]);                \
        gl2lds16(Bh_g + b_goff[0] + k0_, &Bh[BUF][b_ldst[0]]);                \
        gl2lds16(Bh_g + b_goff[1] + k0_, &Bh[BUF][b_ldst[1]]);                \
    } while (0)

    STAGEG(0, 0);

    for (int kt = 0; kt < 16; ++kt) {
        const int cur = kt & 1;
        asm volatile("s_waitcnt vmcnt(0)" ::: "memory");
        __builtin_amdgcn_s_barrier();
        if (kt < 15) STAGEG(cur ^ 1, kt + 1);
#pragma unroll
        for (int ks = 0; ks < 2; ++ks) {
            bf16x8 ah[2], bh[4];
#pragma unroll
            for (int mf = 0; mf < 2; ++mf)
                ah[mf] = *reinterpret_cast<const bf16x8*>(&Ah[cur][aoff[mf][ks]]);
#pragma unroll
            for (int nf = 0; nf < 4; ++nf)
                bh[nf] = *reinterpret_cast<const bf16x8*>(&Bh[cur][boff[nf][ks]]);
#pragma unroll
            for (int mf = 0; mf < 2; ++mf)
#pragma unroll
                for (int nf = 0; nf < 4; ++nf)
                    acc[mf][nf] = __builtin_amdgcn_mfma_f32_16x16x32_bf16(ah[mf], bh[nf], acc[mf][nf], 0, 0, 0);
        }
    }
#undef STAGEG

    const int c = lane & 15;
    const int rq = lane >> 4;
    float bv[4];
#pragma unroll
    for (int nf = 0; nf < 4; ++nf) bv[nf] = bias[n0 + nf * 16 + c];
#pragma unroll
    for (int mf = 0; mf < 2; ++mf) {
        int mbase = m0 + w * 32 + mf * 16 + rq * 4;
#pragma unroll
        for (int nf = 0; nf < 4; ++nf)
#pragma unroll
            for (int r = 0; r < 4; ++r)
                Cf[(size_t)(mbase + r) * DMODEL + n0 + nf * 16 + c] = acc[mf][nf][r] + bv[nf];
    }
}

// ---------------------------------------------------------------------------
// Flash attention (r16 structure) + l-via-ones-MFMA: l = P . 1 computed on
// the matrix pipe (1 extra 32x32 MFMA per kstep), deleting 32 VALU adds/tile
// and the entire cross-lane l-reduce (l lands in acc row layout).
// 32x32 MFMA, in-register P, K dbuf + V ring, deferred PV, 1 barrier/tile.
// ---------------------------------------------------------------------------
__global__ __launch_bounds__(256) void k_attn(const unsigned short* __restrict__ qhi,
                                              const unsigned short* __restrict__ khi,
                                              const unsigned short* __restrict__ vthi,
                                              unsigned short* __restrict__ ch) {
    __shared__ unsigned short Kh[2][64 * 64];
    __shared__ unsigned short Vh[3][64 * 64];   // [d][t], ring

    const int tid  = threadIdx.x;
    const int lane = tid & 63;
    const int w    = tid >> 6;

    int bid = blockIdx.x;
    int wg  = (bid & 7) * 64 + (bid >> 3);      // 512 blocks, 8 XCD chunks
    const int qt = wg & 15;
    const int h  = (wg >> 4) & 15;
    const int b  = wg >> 8;
    const int q0 = qt * 128;

    const int l31 = lane & 31;
    const int lh  = lane >> 5;

    bf16x8 qf[4];
#pragma unroll
    for (int ks = 0; ks < 4; ++ks) {
        int row = q0 + w * 32 + l31;
        qf[ks] = *reinterpret_cast<const bf16x8*>(
            qhi + ((size_t)(b * SEQ + row) * NH + h) * KD + ks * 16 + lh * 8);
    }

    size_t gK[2], gV[2]; int ld_[2];
#pragma unroll
    for (int it = 0; it < 2; ++it) {
        int off = it * 4096 + tid * 16;
        int row = off >> 7;
        int pg = (off >> 4) & 7;
        int lg = pg ^ (row & 7);
        gK[it] = ((size_t)(b * SEQ + row) * NH + h) * KD + lg * 8;
        gV[it] = ((size_t)(b * NH + h) * KD + row) * SEQ + lg * 8;
        ld_[it] = it * 2048 + w * 512;
    }

    int foff[2][4];
#pragma unroll
    for (int tb = 0; tb < 2; ++tb)
#pragma unroll
        for (int ks = 0; ks < 4; ++ks)
            foff[tb][ks] = (tb * 32 + l31) * 64 + (((ks * 2 + lh) ^ (lane & 7)) * 8);

    f32x16 acc[2], l_acc;
#pragma unroll
    for (int db = 0; db < 2; ++db)
#pragma unroll
        for (int r = 0; r < 16; ++r) acc[db][r] = 0.f;
#pragma unroll
    for (int r = 0; r < 16; ++r) l_acc[r] = 0.f;

    unsigned paw[4][4];
    union U8 { unsigned u[4]; bf16x8 v; };
    U8 ones;
    ones.u[0] = 0x3F803F80u; ones.u[1] = 0x3F803F80u;
    ones.u[2] = 0x3F803F80u; ones.u[3] = 0x3F803F80u;

#define STAGE(KB, VB, TT) do {                                               \
        size_t kadv = (size_t)(TT) * 64 * NH * KD;                           \
        size_t vadv = (size_t)(TT) * 64;                                     \
        gl2lds16(khi  + gK[0] + kadv, &Kh[KB][ld_[0]]);                      \
        gl2lds16(khi  + gK[1] + kadv, &Kh[KB][ld_[1]]);                      \
        gl2lds16(vthi + gV[0] + vadv, &Vh[VB][ld_[0]]);                      \
        gl2lds16(vthi + gV[1] + vadv, &Vh[VB][ld_[1]]);                      \
    } while (0)

#define PV_STEP(VSRC) do {                                                   \
        _Pragma("unroll")                                                    \
        for (int ks = 0; ks < 4; ++ks) {                                     \
            U8 pa; pa.u[0] = paw[ks][0]; pa.u[1] = paw[ks][1];               \
            pa.u[2] = paw[ks][2]; pa.u[3] = paw[ks][3];                      \
            _Pragma("unroll")                                                \
            for (int db = 0; db < 2; ++db) {                                 \
                bf16x8 vf = *reinterpret_cast<const bf16x8*>(&Vh[VSRC][foff[db][ks]]); \
                acc[db] = __builtin_amdgcn_mfma_f32_32x32x16_bf16(pa.v, vf, acc[db], 0, 0, 0); \
            }                                                                \
            l_acc = __builtin_amdgcn_mfma_f32_32x32x16_bf16(pa.v, ones.v, l_acc, 0, 0, 0); \
        }                                                                    \
    } while (0)

    STAGE(0, 0, 0);

    int vnext = 1;
    int vprev = 2;

    for (int t = 0; t < 32; ++t) {
        const int ck = t & 1;
        asm volatile("s_waitcnt vmcnt(0)" ::: "memory");
        __builtin_amdgcn_s_barrier();
        if (t < 31) STAGE(ck ^ 1, vnext, t + 1);

        __builtin_amdgcn_s_setprio(1);
        f32x16 s[2];
#pragma unroll
        for (int tb = 0; tb < 2; ++tb) {
#pragma unroll
            for (int r = 0; r < 16; ++r) s[tb][r] = 0.f;
#pragma unroll
            for (int ks = 0; ks < 4; ++ks) {
                bf16x8 kf = *reinterpret_cast<const bf16x8*>(&Kh[ck][foff[tb][ks]]);
                s[tb] = __builtin_amdgcn_mfma_f32_32x32x16_bf16(kf, qf[ks], s[tb], 0, 0, 0);
            }
        }
        if (t > 0) PV_STEP(vprev);
        __builtin_amdgcn_s_setprio(0);

#pragma unroll
        for (int tb = 0; tb < 2; ++tb) {
            float e[16];
#pragma unroll
            for (int r = 0; r < 16; ++r)
                e[r] = exp2_hw(s[tb][r]);
#pragma unroll
            for (int half = 0; half < 2; ++half) {
                unsigned pk01 = cvt_pk_bf16(e[half * 8 + 0], e[half * 8 + 1]);
                unsigned pk23 = cvt_pk_bf16(e[half * 8 + 2], e[half * 8 + 3]);
                unsigned pk45 = cvt_pk_bf16(e[half * 8 + 4], e[half * 8 + 5]);
                unsigned pk67 = cvt_pk_bf16(e[half * 8 + 6], e[half * 8 + 7]);
                asm volatile("v_permlane32_swap_b32 %0, %1" : "+v"(pk01), "+v"(pk45));
                asm volatile("v_permlane32_swap_b32 %0, %1" : "+v"(pk23), "+v"(pk67));
                paw[tb * 2 + half][0] = pk01;
                paw[tb * 2 + half][1] = pk23;
                paw[tb * 2 + half][2] = pk45;
                paw[tb * 2 + half][3] = pk67;
            }
        }

        vnext = (vnext == 2) ? 0 : vnext + 1;
        vprev = (vprev == 2) ? 0 : vprev + 1;
    }

    PV_STEP(vprev);
#undef PV_STEP
#undef STAGE

    // ---- normalize (l_acc rows match acc rows; no shuffles) + store ----
#pragma unroll
    for (int db = 0; db < 2; ++db) {
#pragma unroll
        for (int r = 0; r < 16; ++r) {
            int q = (r & 3) + 8 * (r >> 2) + 4 * lh;
            int qg = q0 + w * 32 + q;
            int d = db * 32 + l31;
            ch[((size_t)(b * SEQ + qg) * NH + h) * KD + d] = f2bf(acc[db][r] / l_acc[r]);
        }
    }
}

// ---------------------------------------------------------------------------
extern "C" void kernel_launch(void* const* d_in, const int* in_sizes, int n_in,
                              void* d_out, int out_size, void* d_ws, size_t ws_size,
                              hipStream_t stream) {
    const float* x  = (const float*)d_in[0];
    const float* Wq = (const float*)d_in[1];
    const float* bq = (const float*)d_in[2];
    const float* Wk = (const float*)d_in[3];
    const float* bk = (const float*)d_in[4];
    const float* Wv = (const float*)d_in[5];
    const float* bv = (const float*)d_in[6];
    const float* Wo = (const float*)d_in[7];
    const float* bo = (const float*)d_in[8];
    float* out = (float*)d_out;

    const size_t NE = (size_t)MROWS * DMODEL;   // 4M
    const size_t WE = (size_t)DMODEL * DMODEL;  // 1M
    float* ws    = (float*)d_ws;
    float* sin_t = ws;
    float* cos_t = sin_t + SEQ * 32;
    unsigned short* p = (unsigned short*)(cos_t + SEQ * 32);
    unsigned short* xh   = p; p += NE;
    unsigned short* qh_  = p; p += NE;
    unsigned short* kh_  = p; p += NE;
    unsigned short* vth  = p; p += NE;
    unsigned short* wth  = p; p += 4 * WE;   // hi pool: [Wq|Wk|Wv|Wo]^T
    unsigned short* ctxh = xh;   // alias: x dead after V projection

    k_prep<<<5376, 256, 0, stream>>>(x, Wq, Wk, Wv, Wo, sin_t, cos_t, xh, wth);

    k_mgemm_qkv<<<512, 256, 0, stream>>>(xh, wth, bq, bk, bv, qh_, kh_, vth, sin_t, cos_t);

    k_attn<<<512, 256, 0, stream>>>(qh_, kh_, vth, ctxh);

    k_mgemm_o<<<512, 256, 0, stream>>>(ctxh, wth + 3 * WE, bo, out);
}